// Round 3
// baseline (1529.636 us; speedup 1.0000x reference)
//
#include <hip/hip_runtime.h>

using u16 = unsigned short;
using u32 = unsigned int;
typedef __attribute__((ext_vector_type(8))) short bf16x8;   // 8 bf16 in 4 VGPRs
typedef __attribute__((ext_vector_type(4))) float f32x4;

constexpr int NN  = 50000;
constexpr int NE  = 800000;
constexpr int DIN = 256;
constexpr int HH  = 256;
constexpr int NL  = 4;
constexpr int NB  = (NN + 255) / 256;      // 196 scan blocks
constexpr int MROW = 50048;                // padded rows (391 * 128)
constexpr float EPS = 1e-5f;

// ---- f32 -> bf16 hi/lo split (compensated representation, ~2^-17 rel) ----
__device__ __forceinline__ void split2(float v, u16& h, u16& l) {
    u32 u  = __float_as_uint(v);
    u32 hu = (u + 0x8000u) >> 16;            // round-half-up to bf16
    float hf = __uint_as_float(hu << 16);
    float d  = v - hf;                        // exact residual
    u32 du = __float_as_uint(d);
    u32 lu = (du + 0x8000u) >> 16;
    h = (u16)hu; l = (u16)lu;
}

__device__ __forceinline__ float bf2f(u16 u) {
    return __uint_as_float(((u32)u) << 16);
}

__global__ void k_split(const float* __restrict__ src, u16* __restrict__ hi,
                        u16* __restrict__ lo, int n) {
    int i = blockIdx.x * 256 + threadIdx.x;
    if (i < n) { u16 h, l; split2(src[i], h, l); hi[i] = h; lo[i] = l; }
}

// ---------------- CSR build (by dst) ----------------

__global__ void k_hist(const int* __restrict__ ei, int* __restrict__ deg) {
    int e = blockIdx.x * 256 + threadIdx.x;
    if (e < NE) atomicAdd(&deg[ei[NE + e]], 1);
}

__global__ __launch_bounds__(256) void k_scan1(const int* __restrict__ deg,
                                               int* __restrict__ tscan,
                                               int* __restrict__ bsum) {
    __shared__ int sm[256];
    const int t = threadIdx.x;
    const int i = blockIdx.x * 256 + t;
    int v = (i < NN) ? deg[i] : 0;
    sm[t] = v;
    __syncthreads();
    #pragma unroll
    for (int off = 1; off < 256; off <<= 1) {
        int add = (t >= off) ? sm[t - off] : 0;
        __syncthreads();
        v += add;
        sm[t] = v;
        __syncthreads();
    }
    tscan[i] = v;                      // inclusive within block
    if (t == 255) bsum[blockIdx.x] = v;
}

__global__ __launch_bounds__(256) void k_scan2(const int* __restrict__ bsum,
                                               int* __restrict__ boff) {
    __shared__ int sm[256];
    const int t = threadIdx.x;
    const int self = (t < NB) ? bsum[t] : 0;
    int v = self;
    sm[t] = v;
    __syncthreads();
    #pragma unroll
    for (int off = 1; off < 256; off <<= 1) {
        int add = (t >= off) ? sm[t - off] : 0;
        __syncthreads();
        v += add;
        sm[t] = v;
        __syncthreads();
    }
    boff[t] = v - self;                // exclusive
}

__global__ __launch_bounds__(256) void k_scan3(const int* __restrict__ deg,
                                               const int* __restrict__ tscan,
                                               const int* __restrict__ boff,
                                               int* __restrict__ row_start,
                                               int* __restrict__ cursor,
                                               float* __restrict__ inv_deg) {
    const int i = blockIdx.x * 256 + threadIdx.x;
    if (i >= NN) { if (i == NN) row_start[NN] = NE; return; }
    const int d = deg[i];
    const int start = boff[blockIdx.x] + tscan[i] - d;
    row_start[i] = start;
    cursor[i] = start;
    inv_deg[i] = 1.0f / (float)max(d, 1);
}

__global__ void k_fill(const int* __restrict__ ei, int* __restrict__ cursor,
                       int* __restrict__ col) {
    int e = blockIdx.x * 256 + threadIdx.x;
    if (e >= NE) return;
    int s = ei[e], d = ei[NE + e];
    int pos = atomicAdd(&cursor[d], 1);
    col[pos] = s;
}

// ---------------- mean aggregation (planes in, planes out) ----------------

__global__ __launch_bounds__(256) void k_aggregate(const u16* __restrict__ hh,
                                                   const u16* __restrict__ hl,
                                                   const int* __restrict__ row_start,
                                                   const int* __restrict__ col,
                                                   const float* __restrict__ inv_deg,
                                                   u16* __restrict__ oh,
                                                   u16* __restrict__ ol) {
    const int node = blockIdx.x * 4 + (threadIdx.x >> 6);
    const int lane = threadIdx.x & 63;
    if (node >= NN) return;
    const int s = row_start[node], e = row_start[node + 1];
    float a0 = 0.f, a1 = 0.f, a2 = 0.f, a3 = 0.f;
    for (int p = s; p < e; ++p) {
        const size_t b = (size_t)col[p] * HH + lane * 4;
        const ushort4 hv = *(const ushort4*)&hh[b];
        const ushort4 lv = *(const ushort4*)&hl[b];
        a0 += bf2f(hv.x) + bf2f(lv.x);
        a1 += bf2f(hv.y) + bf2f(lv.y);
        a2 += bf2f(hv.z) + bf2f(lv.z);
        a3 += bf2f(hv.w) + bf2f(lv.w);
    }
    const float g = inv_deg[node];
    u16 h0, l0, h1, l1, h2, l2, h3, l3;
    split2(a0 * g, h0, l0); split2(a1 * g, h1, l1);
    split2(a2 * g, h2, l2); split2(a3 * g, h3, l3);
    const size_t ob = (size_t)node * HH + lane * 4;
    *(ushort4*)&oh[ob] = ushort4{h0, h1, h2, h3};
    *(ushort4*)&ol[ob] = ushort4{l0, l1, l2, l3};
}

// ---------------- compensated bf16 MFMA GEMM (planes in) ----------------
// C[m,j] = sum_k A[m,k]*W[j,k] (+bias)(+relu(BN(D)))(+relu)
// acc += Ah*Wh + Ah*Wl + Al*Wh. All tiles staged via global_load_lds.
// K spans two sources at k=256. 128x128 tile, BK=32, 4 waves (2x2).

template<bool RELU, bool BNADD, bool WF32, bool WPL>
__global__ __launch_bounds__(256, 2) void k_gemm_mfma(
    int M, int K, int J, int lda, int ldw,
    const u16* __restrict__ Ah0, const u16* __restrict__ Al0,
    const u16* __restrict__ Ah1, const u16* __restrict__ Al1,
    const u16* __restrict__ Wh0, const u16* __restrict__ Wl0,
    const u16* __restrict__ Wh1, const u16* __restrict__ Wl1,
    const float* __restrict__ bias,
    const float* __restrict__ D, const float* __restrict__ scsh,
    float* __restrict__ Cf, u16* __restrict__ Ch, u16* __restrict__ Cl)
{
    __shared__ u16 AhL[128 * 32];
    __shared__ u16 AlL[128 * 32];
    __shared__ u16 BhL[128 * 32];
    __shared__ u16 BlL[128 * 32];

    const int tid  = threadIdx.x;
    const int w    = tid >> 6;
    const int lane = tid & 63;
    const int m0 = blockIdx.x * 128;
    const int j0 = blockIdx.y * 128;
    const int wm = w >> 1, wn = w & 1;
    const int lr = lane & 15, lk = lane >> 4;
    const int cr = lane >> 2;          // row within 16-row chunk
    const int ck = (lane & 3) * 8;     // k offset (u16) within chunk row

    f32x4 acc[4][4];
    #pragma unroll
    for (int mi = 0; mi < 4; ++mi)
        #pragma unroll
        for (int ni = 0; ni < 4; ++ni)
            acc[mi][ni] = f32x4{0.f, 0.f, 0.f, 0.f};

    for (int k0 = 0; k0 < K; k0 += 32) {
        const int kc = k0 & 255;
        const u16* Ah = (k0 < 256) ? Ah0 : Ah1;
        const u16* Al = (k0 < 256) ? Al0 : Al1;
        const u16* Wh = (k0 < 256) ? Wh0 : Wh1;
        const u16* Wl = (k0 < 256) ? Wl0 : Wl1;

        __syncthreads();   // previous tile fully consumed
        #pragma unroll
        for (int i = 0; i < 2; ++i) {
            const int c = w + i * 4;               // chunk 0..7 (16 rows each)
            const int r = 16 * c + cr;
            const size_t ga = (size_t)(m0 + r) * lda + kc + ck;
            const size_t gb = (size_t)(j0 + r) * ldw + kc + ck;
            __builtin_amdgcn_global_load_lds(
                (const __attribute__((address_space(1))) void*)(Ah + ga),
                (__attribute__((address_space(3))) void*)&AhL[c * 512], 16, 0, 0);
            __builtin_amdgcn_global_load_lds(
                (const __attribute__((address_space(1))) void*)(Al + ga),
                (__attribute__((address_space(3))) void*)&AlL[c * 512], 16, 0, 0);
            __builtin_amdgcn_global_load_lds(
                (const __attribute__((address_space(1))) void*)(Wh + gb),
                (__attribute__((address_space(3))) void*)&BhL[c * 512], 16, 0, 0);
            __builtin_amdgcn_global_load_lds(
                (const __attribute__((address_space(1))) void*)(Wl + gb),
                (__attribute__((address_space(3))) void*)&BlL[c * 512], 16, 0, 0);
        }
        __syncthreads();   // vmcnt drained by barrier -> tiles ready

        bf16x8 ah[4], al[4], bh[4], bl[4];
        #pragma unroll
        for (int mi = 0; mi < 4; ++mi) {
            const int off = (wm * 64 + mi * 16 + lr) * 32 + lk * 8;
            ah[mi] = *(const bf16x8*)&AhL[off];
            al[mi] = *(const bf16x8*)&AlL[off];
        }
        #pragma unroll
        for (int ni = 0; ni < 4; ++ni) {
            const int off = (wn * 64 + ni * 16 + lr) * 32 + lk * 8;
            bh[ni] = *(const bf16x8*)&BhL[off];
            bl[ni] = *(const bf16x8*)&BlL[off];
        }
        #pragma unroll
        for (int mi = 0; mi < 4; ++mi)
            #pragma unroll
            for (int ni = 0; ni < 4; ++ni) {
                acc[mi][ni] = __builtin_amdgcn_mfma_f32_16x16x32_bf16(
                    ah[mi], bh[ni], acc[mi][ni], 0, 0, 0);
                acc[mi][ni] = __builtin_amdgcn_mfma_f32_16x16x32_bf16(
                    ah[mi], bl[ni], acc[mi][ni], 0, 0, 0);
                acc[mi][ni] = __builtin_amdgcn_mfma_f32_16x16x32_bf16(
                    al[mi], bh[ni], acc[mi][ni], 0, 0, 0);
            }
    }

    // epilogue: C/D frag layout col=lane&15, row=(lane>>4)*4+r
    #pragma unroll
    for (int mi = 0; mi < 4; ++mi) {
        #pragma unroll
        for (int ni = 0; ni < 4; ++ni) {
            const int colj = j0 + wn * 64 + ni * 16 + lr;
            const float bv = bias[colj];
            float sc = 0.f, sh = 0.f;
            if (BNADD) { sc = scsh[colj]; sh = scsh[HH + colj]; }
            #pragma unroll
            for (int r = 0; r < 4; ++r) {
                const int row = m0 + wm * 64 + mi * 16 + lk * 4 + r;
                if (row >= M) continue;
                float v = acc[mi][ni][r] + bv;
                if (BNADD) {
                    const float dv = D[(size_t)row * J + colj];
                    v += fmaxf(dv * sc + sh, 0.f);
                }
                if (RELU) v = fmaxf(v, 0.f);
                if (WF32) Cf[(size_t)row * J + colj] = v;
                if (WPL) {
                    u16 hh, ll; split2(v, hh, ll);
                    Ch[(size_t)row * J + colj] = hh;
                    Cl[(size_t)row * J + colj] = ll;
                }
            }
        }
    }
}

// ---------------- BatchNorm stats ----------------

__global__ __launch_bounds__(256) void k_bn_stats(const float* __restrict__ X,
                                                  float* __restrict__ stats) {
    const int colj = threadIdx.x;
    const int RPB = (NN + gridDim.x - 1) / gridDim.x;
    const int r0 = blockIdx.x * RPB;
    const int r1 = min(r0 + RPB, NN);
    float s = 0.f, ss = 0.f;
    for (int r = r0; r < r1; ++r) {
        float v = X[(size_t)r * HH + colj];
        s += v;
        ss = fmaf(v, v, ss);
    }
    atomicAdd(&stats[colj], s);
    atomicAdd(&stats[HH + colj], ss);
}

__global__ void k_bn_finalize(const float* __restrict__ stats,
                              const float* __restrict__ g,
                              const float* __restrict__ b,
                              float* __restrict__ scsh) {
    const int j = threadIdx.x;
    const float inv_n = 1.0f / (float)NN;
    const float mu = stats[j] * inv_n;
    const float var = stats[HH + j] * inv_n - mu * mu;
    const float rstd = rsqrtf(var + EPS);
    const float sc = g[j] * rstd;
    scsh[j] = sc;
    scsh[HH + j] = b[j] - mu * sc;
}

// ---------------- out proj (DOUT=2) + log_softmax ----------------

__global__ __launch_bounds__(256) void k_out(const float* __restrict__ h,
                                             const float* __restrict__ ow,
                                             const float* __restrict__ ob,
                                             float* __restrict__ out) {
    const int row = blockIdx.x * 4 + (threadIdx.x >> 6);
    const int lane = threadIdx.x & 63;
    if (row >= NN) return;
    const float4 hv = *(const float4*)&h[(size_t)row * HH + lane * 4];
    const float4 w0 = *(const float4*)&ow[lane * 4];
    const float4 w1 = *(const float4*)&ow[HH + lane * 4];
    float p0 = hv.x * w0.x + hv.y * w0.y + hv.z * w0.z + hv.w * w0.w;
    float p1 = hv.x * w1.x + hv.y * w1.y + hv.z * w1.z + hv.w * w1.w;
    #pragma unroll
    for (int off = 32; off >= 1; off >>= 1) {
        p0 += __shfl_down(p0, off);
        p1 += __shfl_down(p1, off);
    }
    if (lane == 0) {
        p0 += ob[0]; p1 += ob[1];
        const float m = fmaxf(p0, p1);
        const float lse = m + logf(__expf(p0 - m) + __expf(p1 - m));
        out[(size_t)row * 2 + 0] = p0 - lse;
        out[(size_t)row * 2 + 1] = p1 - lse;
    }
}

// ---------------- host ----------------

template<bool RELU, bool BNADD, bool WF32, bool WPL>
static void launch_mfma(int M, int K, int J, int lda, int ldw,
                        const u16* Ah0, const u16* Al0,
                        const u16* Ah1, const u16* Al1,
                        const u16* Wh0, const u16* Wl0,
                        const u16* Wh1, const u16* Wl1,
                        const float* bias, const float* D, const float* scsh,
                        float* Cf, u16* Ch, u16* Cl, hipStream_t stream) {
    dim3 grid((M + 127) / 128, J / 128);
    k_gemm_mfma<RELU, BNADD, WF32, WPL><<<grid, 256, 0, stream>>>(
        M, K, J, lda, ldw, Ah0, Al0, Ah1, Al1, Wh0, Wl0, Wh1, Wl1,
        bias, D, scsh, Cf, Ch, Cl);
}

extern "C" void kernel_launch(void* const* d_in, const int* in_sizes, int n_in,
                              void* d_out, int out_size, void* d_ws, size_t ws_size,
                              hipStream_t stream) {
    const float* x       = (const float*)d_in[0];
    const int*   ei      = (const int*)d_in[1];
    const float* in_w    = (const float*)d_in[2];
    const float* in_b    = (const float*)d_in[3];
    const float* conv_wl = (const float*)d_in[4];
    const float* conv_bl = (const float*)d_in[5];
    const float* conv_wr = (const float*)d_in[6];
    const float* bn_g    = (const float*)d_in[7];
    const float* bn_b    = (const float*)d_in[8];
    const float* skip_w  = (const float*)d_in[9];
    const float* skip_b  = (const float*)d_in[10];
    const float* mlp_w1  = (const float*)d_in[11];
    const float* mlp_b1  = (const float*)d_in[12];
    const float* mlp_w2  = (const float*)d_in[13];
    const float* mlp_b2  = (const float*)d_in[14];
    const float* out_w   = (const float*)d_in[15];
    const float* out_b   = (const float*)d_in[16];
    float* out = (float*)d_out;
    (void)in_sizes; (void)n_in; (void)out_size; (void)ws_size;

    char* base = (char*)d_ws;
    size_t off = 0;
    auto alloc = [&](size_t bytes) -> void* {
        void* p = base + off;
        off += (bytes + 255) & ~(size_t)255;
        return p;
    };
    // CSR / scan scratch
    int*   deg   = (int*)alloc((size_t)NN * sizeof(int));
    int*   rs    = (int*)alloc((size_t)(NN + 1) * sizeof(int));
    int*   cur   = (int*)alloc((size_t)NN * sizeof(int));
    int*   col   = (int*)alloc((size_t)NE * sizeof(int));
    int*   tscan = (int*)alloc((size_t)NB * 256 * sizeof(int));
    int*   bsum  = (int*)alloc(256 * sizeof(int));
    int*   boff  = (int*)alloc(256 * sizeof(int));
    float* idg   = (float*)alloc((size_t)NN * sizeof(float));
    float* stats = (float*)alloc(2 * HH * sizeof(float));
    float* scsh  = (float*)alloc(2 * HH * sizeof(float));
    // bf16 weight planes (hi/lo)
    u16* win_h = (u16*)alloc(65536 * sizeof(u16));
    u16* win_l = (u16*)alloc(65536 * sizeof(u16));
    u16* wl_h  = (u16*)alloc(4 * 65536 * sizeof(u16));
    u16* wl_l  = (u16*)alloc(4 * 65536 * sizeof(u16));
    u16* wr_h  = (u16*)alloc(4 * 65536 * sizeof(u16));
    u16* wr_l  = (u16*)alloc(4 * 65536 * sizeof(u16));
    u16* wsk_h = (u16*)alloc(4 * 65536 * sizeof(u16));
    u16* wsk_l = (u16*)alloc(4 * 65536 * sizeof(u16));
    u16* m1_h  = (u16*)alloc(131072 * sizeof(u16));
    u16* m1_l  = (u16*)alloc(131072 * sizeof(u16));
    u16* m2_h  = (u16*)alloc(131072 * sizeof(u16));
    u16* m2_l  = (u16*)alloc(131072 * sizeof(u16));
    // activation planes (MROW-padded). px/pa contiguous -> aliased by pm.
    const size_t PEL = (size_t)MROW * HH;          // 12.8M u16 = 25.6MB
    u16* px_h = (u16*)alloc(PEL * sizeof(u16));
    u16* px_l = (u16*)alloc(PEL * sizeof(u16));
    u16* pa_h = (u16*)alloc(PEL * sizeof(u16));
    u16* pa_l = (u16*)alloc(PEL * sizeof(u16));
    u16* ph0_h = (u16*)alloc(PEL * sizeof(u16));
    u16* ph0_l = (u16*)alloc(PEL * sizeof(u16));
    u16* ph1_h = (u16*)alloc(PEL * sizeof(u16));
    u16* ph1_l = (u16*)alloc(PEL * sizeof(u16));
    float* pcv = (float*)alloc((size_t)MROW * HH * sizeof(float));  // conv f32 / final h
    // mid planes (MROW x 512) alias px/pa region (dead by MLP time)
    u16* pm_h = px_h;
    u16* pm_l = pa_h;

    // weight splits
    k_split<<<(65536 + 255) / 256, 256, 0, stream>>>(in_w, win_h, win_l, 65536);
    k_split<<<(262144 + 255) / 256, 256, 0, stream>>>(conv_wl, wl_h, wl_l, 262144);
    k_split<<<(262144 + 255) / 256, 256, 0, stream>>>(conv_wr, wr_h, wr_l, 262144);
    k_split<<<(262144 + 255) / 256, 256, 0, stream>>>(skip_w, wsk_h, wsk_l, 262144);
    k_split<<<(131072 + 255) / 256, 256, 0, stream>>>(mlp_w1, m1_h, m1_l, 131072);
    k_split<<<(131072 + 255) / 256, 256, 0, stream>>>(mlp_w2, m2_h, m2_l, 131072);
    // input split
    k_split<<<(NN * 256 + 255) / 256, 256, 0, stream>>>(x, px_h, px_l, NN * 256);

    // CSR build (parallel scan)
    hipMemsetAsync(deg, 0, (size_t)NN * sizeof(int), stream);
    k_hist<<<(NE + 255) / 256, 256, 0, stream>>>(ei, deg);
    k_scan1<<<NB, 256, 0, stream>>>(deg, tscan, bsum);
    k_scan2<<<1, 256, 0, stream>>>(bsum, boff);
    k_scan3<<<NB, 256, 0, stream>>>(deg, tscan, boff, rs, cur, idg);
    k_fill<<<(NE + 255) / 256, 256, 0, stream>>>(ei, cur, col);

    // input projection + ReLU -> ph0 planes
    launch_mfma<true, false, false, true>(NN, 256, 256, 256, 256,
        px_h, px_l, px_h, px_l, win_h, win_l, win_h, win_l,
        in_b, nullptr, nullptr, nullptr, ph0_h, ph0_l, stream);

    u16* hc_h = ph0_h; u16* hc_l = ph0_l;
    u16* hn_h = ph1_h; u16* hn_l = ph1_l;
    for (int l = 0; l < NL; ++l) {
        k_aggregate<<<(NN + 3) / 4, 256, 0, stream>>>(hc_h, hc_l, rs, col, idg, pa_h, pa_l);
        // conv = [agg | h] @ [wl | wr]^T + bl  (K=512 concat) -> pcv f32
        launch_mfma<false, false, true, false>(NN, 512, 256, 256, 256,
            pa_h, pa_l, hc_h, hc_l,
            wl_h + (size_t)l * 65536, wl_l + (size_t)l * 65536,
            wr_h + (size_t)l * 65536, wr_l + (size_t)l * 65536,
            conv_bl + l * HH, nullptr, nullptr, pcv, nullptr, nullptr, stream);
        hipMemsetAsync(stats, 0, 2 * HH * sizeof(float), stream);
        k_bn_stats<<<1024, 256, 0, stream>>>(pcv, stats);
        k_bn_finalize<<<1, 256, 0, stream>>>(stats, bn_g + l * HH, bn_b + l * HH, scsh);
        // h_next = relu(BN(conv)) + h @ skip_w^T + skip_b -> planes
        launch_mfma<false, true, false, true>(NN, 256, 256, 256, 256,
            hc_h, hc_l, hc_h, hc_l,
            wsk_h + (size_t)l * 65536, wsk_l + (size_t)l * 65536,
            wsk_h + (size_t)l * 65536, wsk_l + (size_t)l * 65536,
            skip_b + l * HH, pcv, scsh, nullptr, hn_h, hn_l, stream);
        u16* t;
        t = hc_h; hc_h = hn_h; hn_h = t;
        t = hc_l; hc_l = hn_l; hn_l = t;
    }
    // MLP hidden = relu(h @ w1^T + b1) -> pm planes (MROW x 512)
    launch_mfma<true, false, false, true>(NN, 256, 512, 256, 256,
        hc_h, hc_l, hc_h, hc_l, m1_h, m1_l, m1_h, m1_l,
        mlp_b1, nullptr, nullptr, nullptr, pm_h, pm_l, stream);
    // h = hidden @ w2^T + b2 -> pcv f32 (K=512 contiguous)
    launch_mfma<false, false, true, false>(NN, 512, 256, 512, 512,
        pm_h, pm_l, pm_h + 256, pm_l + 256,
        m2_h, m2_l, m2_h + 256, m2_l + 256,
        mlp_b2, nullptr, nullptr, pcv, nullptr, nullptr, stream);

    k_out<<<(NN + 3) / 4, 256, 0, stream>>>(pcv, out_w, out_b, out);
}

// Round 4
// 956.869 us; speedup vs baseline: 1.5986x; 1.5986x over previous
//
#include <hip/hip_runtime.h>

using u16 = unsigned short;
using u32 = unsigned int;
typedef _Float16 f16;
typedef __attribute__((ext_vector_type(8))) _Float16 f16x8;
typedef __attribute__((ext_vector_type(4))) _Float16 f16x4;
typedef __attribute__((ext_vector_type(4))) float f32x4;

constexpr int NN  = 50000;
constexpr int NE  = 800000;
constexpr int HH  = 256;
constexpr int NL  = 4;
constexpr int NB  = (NN + 255) / 256;      // 196 scan blocks
constexpr int MROW = 50048;                // padded rows (391 * 128)
constexpr float EPS = 1e-5f;

__device__ __forceinline__ u16 f2h(float x) {
    return __builtin_bit_cast(u16, (f16)x);
}
__device__ __forceinline__ float h2f(u16 u) {
    return (float)__builtin_bit_cast(f16, u);
}

// ---- f32 -> f16 convert, 8 elems/thread ----
__global__ void k_cvt(const float* __restrict__ src, u16* __restrict__ dst, int n8) {
    int i = blockIdx.x * 256 + threadIdx.x;
    if (i >= n8) return;
    const float4 a = ((const float4*)src)[2 * i];
    const float4 b = ((const float4*)src)[2 * i + 1];
    ushort4 lo, hi;
    lo.x = f2h(a.x); lo.y = f2h(a.y); lo.z = f2h(a.z); lo.w = f2h(a.w);
    hi.x = f2h(b.x); hi.y = f2h(b.y); hi.z = f2h(b.z); hi.w = f2h(b.w);
    ((ushort4*)dst)[2 * i] = lo;
    ((ushort4*)dst)[2 * i + 1] = hi;
}

// ---------------- CSR build (by dst) ----------------

__global__ void k_hist(const int* __restrict__ ei, int* __restrict__ deg) {
    int e = blockIdx.x * 256 + threadIdx.x;
    if (e < NE) atomicAdd(&deg[ei[NE + e]], 1);
}

__global__ __launch_bounds__(256) void k_scan1(const int* __restrict__ deg,
                                               int* __restrict__ tscan,
                                               int* __restrict__ bsum) {
    __shared__ int sm[256];
    const int t = threadIdx.x;
    const int i = blockIdx.x * 256 + t;
    int v = (i < NN) ? deg[i] : 0;
    sm[t] = v;
    __syncthreads();
    #pragma unroll
    for (int off = 1; off < 256; off <<= 1) {
        int add = (t >= off) ? sm[t - off] : 0;
        __syncthreads();
        v += add;
        sm[t] = v;
        __syncthreads();
    }
    tscan[i] = v;
    if (t == 255) bsum[blockIdx.x] = v;
}

__global__ __launch_bounds__(256) void k_scan2(const int* __restrict__ bsum,
                                               int* __restrict__ boff) {
    __shared__ int sm[256];
    const int t = threadIdx.x;
    const int self = (t < NB) ? bsum[t] : 0;
    int v = self;
    sm[t] = v;
    __syncthreads();
    #pragma unroll
    for (int off = 1; off < 256; off <<= 1) {
        int add = (t >= off) ? sm[t - off] : 0;
        __syncthreads();
        v += add;
        sm[t] = v;
        __syncthreads();
    }
    boff[t] = v - self;
}

__global__ __launch_bounds__(256) void k_scan3(const int* __restrict__ deg,
                                               const int* __restrict__ tscan,
                                               const int* __restrict__ boff,
                                               int* __restrict__ row_start,
                                               int* __restrict__ cursor,
                                               float* __restrict__ inv_deg) {
    const int i = blockIdx.x * 256 + threadIdx.x;
    if (i >= NN) { if (i == NN) row_start[NN] = NE; return; }
    const int d = deg[i];
    const int start = boff[blockIdx.x] + tscan[i] - d;
    row_start[i] = start;
    cursor[i] = start;
    inv_deg[i] = 1.0f / (float)max(d, 1);
}

__global__ void k_fill(const int* __restrict__ ei, int* __restrict__ cursor,
                       int* __restrict__ col) {
    int e = blockIdx.x * 256 + threadIdx.x;
    if (e >= NE) return;
    int s = ei[e], d = ei[NE + e];
    int pos = atomicAdd(&cursor[d], 1);
    col[pos] = s;
}

// ---------------- mean aggregation: one wave per node, f16 rows ----------------

__global__ __launch_bounds__(256) void k_aggregate(const u16* __restrict__ h,
                                                   const int* __restrict__ row_start,
                                                   const int* __restrict__ col,
                                                   const float* __restrict__ inv_deg,
                                                   u16* __restrict__ o) {
    const int node = blockIdx.x * 4 + (threadIdx.x >> 6);
    const int lane = threadIdx.x & 63;
    if (node >= NN) return;
    const int s = row_start[node], e = row_start[node + 1];
    float a0 = 0.f, a1 = 0.f, a2 = 0.f, a3 = 0.f;
    int p = s;
    for (; p + 3 < e; p += 4) {
        const int c0 = col[p], c1 = col[p + 1], c2 = col[p + 2], c3 = col[p + 3];
        const f16x4 v0 = *(const f16x4*)&h[(size_t)c0 * HH + lane * 4];
        const f16x4 v1 = *(const f16x4*)&h[(size_t)c1 * HH + lane * 4];
        const f16x4 v2 = *(const f16x4*)&h[(size_t)c2 * HH + lane * 4];
        const f16x4 v3 = *(const f16x4*)&h[(size_t)c3 * HH + lane * 4];
        a0 += (float)v0[0] + (float)v1[0] + (float)v2[0] + (float)v3[0];
        a1 += (float)v0[1] + (float)v1[1] + (float)v2[1] + (float)v3[1];
        a2 += (float)v0[2] + (float)v1[2] + (float)v2[2] + (float)v3[2];
        a3 += (float)v0[3] + (float)v1[3] + (float)v2[3] + (float)v3[3];
    }
    for (; p < e; ++p) {
        const f16x4 v0 = *(const f16x4*)&h[(size_t)col[p] * HH + lane * 4];
        a0 += (float)v0[0]; a1 += (float)v0[1];
        a2 += (float)v0[2]; a3 += (float)v0[3];
    }
    const float g = inv_deg[node];
    f16x4 r;
    r[0] = (f16)(a0 * g); r[1] = (f16)(a1 * g);
    r[2] = (f16)(a2 * g); r[3] = (f16)(a3 * g);
    *(f16x4*)&o[(size_t)node * HH + lane * 4] = r;
}

// ---------------- f16 MFMA GEMM ----------------
// C[m,j] = sum_k A[m,k]*W[j,k] (+bias)(+relu(BN(D)))(+relu)
// 128x128 tile, BK=64, 4 waves (2x2), 16x16x32 f16 MFMA, 3 blocks/CU.
// LDS tiles [128 rows][64 k] u16; 16B slots XOR-swizzled: logical slot s of
// row r stored at phys slot s^(r&7). gload_lds dest is linear; the swizzle is
// applied by permuting the per-lane GLOBAL source (rule: both-sides-or-neither).

template<bool RELU, bool BNADD, bool WF32, bool WPH>
__global__ __launch_bounds__(256, 3) void k_gemm_f16(
    int M, int K, int J, int lda, int ldw,
    const u16* __restrict__ A0, const u16* __restrict__ A1,
    const u16* __restrict__ W0, const u16* __restrict__ W1,
    const float* __restrict__ bias,
    const float* __restrict__ D, const float* __restrict__ scsh,
    float* __restrict__ Cf, u16* __restrict__ Ch)
{
    __shared__ u16 AL[128 * 64];
    __shared__ u16 BL[128 * 64];

    const int tid  = threadIdx.x;
    const int w    = tid >> 6;
    const int lane = tid & 63;
    const int m0 = blockIdx.x * 128;
    const int j0 = blockIdx.y * 128;
    const int wm = w >> 1, wn = w & 1;
    const int lr = lane & 15, lk = lane >> 4;
    // staging: chunk = 8 rows x 64k (1KB). lane -> row lane>>3, phys slot lane&7.
    const int srow  = lane >> 3;
    const int sslot = (lane & 7) ^ srow;    // logical 16B slot this lane fetches

    f32x4 acc[4][4];
    #pragma unroll
    for (int mi = 0; mi < 4; ++mi)
        #pragma unroll
        for (int ni = 0; ni < 4; ++ni)
            acc[mi][ni] = f32x4{0.f, 0.f, 0.f, 0.f};

    for (int k0 = 0; k0 < K; k0 += 64) {
        const u16* A = (k0 < 256) ? A0 : A1;
        const u16* W = (k0 < 256) ? W0 : W1;
        const int kc = k0 & 255;

        __syncthreads();   // previous tile fully consumed
        #pragma unroll
        for (int i = 0; i < 4; ++i) {
            const int c = w * 4 + i;            // chunk 0..15
            const int r = c * 8 + srow;
            const size_t ga = (size_t)(m0 + r) * lda + kc + sslot * 8;
            const size_t gb = (size_t)(j0 + r) * ldw + kc + sslot * 8;
            __builtin_amdgcn_global_load_lds(
                (const __attribute__((address_space(1))) void*)(A + ga),
                (__attribute__((address_space(3))) void*)&AL[c * 512], 16, 0, 0);
            __builtin_amdgcn_global_load_lds(
                (const __attribute__((address_space(1))) void*)(W + gb),
                (__attribute__((address_space(3))) void*)&BL[c * 512], 16, 0, 0);
        }
        __syncthreads();   // tiles ready

        #pragma unroll
        for (int kh = 0; kh < 2; ++kh) {       // two K=32 halves
            f16x8 af[4], bfr[4];
            #pragma unroll
            for (int mi = 0; mi < 4; ++mi) {
                const int row = wm * 64 + mi * 16 + lr;
                const int slot = (kh * 4 + lk) ^ (row & 7);
                af[mi] = *(const f16x8*)&AL[row * 64 + slot * 8];
            }
            #pragma unroll
            for (int ni = 0; ni < 4; ++ni) {
                const int row = wn * 64 + ni * 16 + lr;
                const int slot = (kh * 4 + lk) ^ (row & 7);
                bfr[ni] = *(const f16x8*)&BL[row * 64 + slot * 8];
            }
            #pragma unroll
            for (int mi = 0; mi < 4; ++mi)
                #pragma unroll
                for (int ni = 0; ni < 4; ++ni)
                    acc[mi][ni] = __builtin_amdgcn_mfma_f32_16x16x32_f16(
                        af[mi], bfr[ni], acc[mi][ni], 0, 0, 0);
        }
    }

    // epilogue: C/D frag layout col=lane&15, row=(lane>>4)*4+r
    #pragma unroll
    for (int mi = 0; mi < 4; ++mi) {
        #pragma unroll
        for (int ni = 0; ni < 4; ++ni) {
            const int colj = j0 + wn * 64 + ni * 16 + lr;
            const float bv = bias[colj];
            float sc = 0.f, sh = 0.f;
            if (BNADD) { sc = scsh[colj]; sh = scsh[HH + colj]; }
            #pragma unroll
            for (int r = 0; r < 4; ++r) {
                const int row = m0 + wm * 64 + mi * 16 + lk * 4 + r;
                if (row >= M) continue;
                float v = acc[mi][ni][r] + bv;
                if (BNADD) {
                    const float dv = D[(size_t)row * J + colj];
                    v += fmaxf(dv * sc + sh, 0.f);
                }
                if (RELU) v = fmaxf(v, 0.f);
                if (WF32) Cf[(size_t)row * J + colj] = v;
                if (WPH)  Ch[(size_t)row * J + colj] = f2h(v);
            }
        }
    }
}

// ---------------- BatchNorm stats ----------------

__global__ __launch_bounds__(256) void k_bn_stats(const float* __restrict__ X,
                                                  float* __restrict__ stats) {
    const int colj = threadIdx.x;
    const int RPB = (NN + gridDim.x - 1) / gridDim.x;
    const int r0 = blockIdx.x * RPB;
    const int r1 = min(r0 + RPB, NN);
    float s = 0.f, ss = 0.f;
    for (int r = r0; r < r1; ++r) {
        float v = X[(size_t)r * HH + colj];
        s += v;
        ss = fmaf(v, v, ss);
    }
    atomicAdd(&stats[colj], s);
    atomicAdd(&stats[HH + colj], ss);
}

__global__ void k_bn_finalize(const float* __restrict__ stats,
                              const float* __restrict__ g,
                              const float* __restrict__ b,
                              float* __restrict__ scsh) {
    const int j = threadIdx.x;
    const float inv_n = 1.0f / (float)NN;
    const float mu = stats[j] * inv_n;
    const float var = stats[HH + j] * inv_n - mu * mu;
    const float rstd = rsqrtf(var + EPS);
    const float sc = g[j] * rstd;
    scsh[j] = sc;
    scsh[HH + j] = b[j] - mu * sc;
}

// ---------------- out proj (DOUT=2) + log_softmax ----------------

__global__ __launch_bounds__(256) void k_out(const float* __restrict__ h,
                                             const float* __restrict__ ow,
                                             const float* __restrict__ ob,
                                             float* __restrict__ out) {
    const int row = blockIdx.x * 4 + (threadIdx.x >> 6);
    const int lane = threadIdx.x & 63;
    if (row >= NN) return;
    const float4 hv = *(const float4*)&h[(size_t)row * HH + lane * 4];
    const float4 w0 = *(const float4*)&ow[lane * 4];
    const float4 w1 = *(const float4*)&ow[HH + lane * 4];
    float p0 = hv.x * w0.x + hv.y * w0.y + hv.z * w0.z + hv.w * w0.w;
    float p1 = hv.x * w1.x + hv.y * w1.y + hv.z * w1.z + hv.w * w1.w;
    #pragma unroll
    for (int off = 32; off >= 1; off >>= 1) {
        p0 += __shfl_down(p0, off);
        p1 += __shfl_down(p1, off);
    }
    if (lane == 0) {
        p0 += ob[0]; p1 += ob[1];
        const float m = fmaxf(p0, p1);
        const float lse = m + logf(__expf(p0 - m) + __expf(p1 - m));
        out[(size_t)row * 2 + 0] = p0 - lse;
        out[(size_t)row * 2 + 1] = p1 - lse;
    }
}

// ---------------- host ----------------

template<bool RELU, bool BNADD, bool WF32, bool WPH>
static void launch_gemm(int M, int K, int J, int lda, int ldw,
                        const u16* A0, const u16* A1,
                        const u16* W0, const u16* W1,
                        const float* bias, const float* D, const float* scsh,
                        float* Cf, u16* Ch, hipStream_t stream) {
    dim3 grid((M + 127) / 128, J / 128);
    k_gemm_f16<RELU, BNADD, WF32, WPH><<<grid, 256, 0, stream>>>(
        M, K, J, lda, ldw, A0, A1, W0, W1, bias, D, scsh, Cf, Ch);
}

extern "C" void kernel_launch(void* const* d_in, const int* in_sizes, int n_in,
                              void* d_out, int out_size, void* d_ws, size_t ws_size,
                              hipStream_t stream) {
    const float* x       = (const float*)d_in[0];
    const int*   ei      = (const int*)d_in[1];
    const float* in_w    = (const float*)d_in[2];
    const float* in_b    = (const float*)d_in[3];
    const float* conv_wl = (const float*)d_in[4];
    const float* conv_bl = (const float*)d_in[5];
    const float* conv_wr = (const float*)d_in[6];
    const float* bn_g    = (const float*)d_in[7];
    const float* bn_b    = (const float*)d_in[8];
    const float* skip_w  = (const float*)d_in[9];
    const float* skip_b  = (const float*)d_in[10];
    const float* mlp_w1  = (const float*)d_in[11];
    const float* mlp_b1  = (const float*)d_in[12];
    const float* mlp_w2  = (const float*)d_in[13];
    const float* mlp_b2  = (const float*)d_in[14];
    const float* out_w   = (const float*)d_in[15];
    const float* out_b   = (const float*)d_in[16];
    float* out = (float*)d_out;
    (void)in_sizes; (void)n_in; (void)out_size; (void)ws_size;

    char* base = (char*)d_ws;
    size_t off = 0;
    auto alloc = [&](size_t bytes) -> void* {
        void* p = base + off;
        off += (bytes + 255) & ~(size_t)255;
        return p;
    };
    // CSR / scan scratch
    int*   deg   = (int*)alloc((size_t)NN * sizeof(int));
    int*   rs    = (int*)alloc((size_t)(NN + 1) * sizeof(int));
    int*   cur   = (int*)alloc((size_t)NN * sizeof(int));
    int*   col   = (int*)alloc((size_t)NE * sizeof(int));
    int*   tscan = (int*)alloc((size_t)NB * 256 * sizeof(int));
    int*   bsum  = (int*)alloc(256 * sizeof(int));
    int*   boff  = (int*)alloc(256 * sizeof(int));
    float* idg   = (float*)alloc((size_t)NN * sizeof(float));
    float* stats = (float*)alloc(2 * HH * sizeof(float));
    float* scsh  = (float*)alloc(2 * HH * sizeof(float));
    // f16 weights
    u16* win = (u16*)alloc(65536 * sizeof(u16));
    u16* wl  = (u16*)alloc(4 * 65536 * sizeof(u16));
    u16* wr  = (u16*)alloc(4 * 65536 * sizeof(u16));
    u16* wsk = (u16*)alloc(4 * 65536 * sizeof(u16));
    u16* m1  = (u16*)alloc(131072 * sizeof(u16));
    u16* m2  = (u16*)alloc(131072 * sizeof(u16));
    // f16 activations (MROW-padded)
    const size_t PEL = (size_t)MROW * HH;
    u16* px  = (u16*)alloc(PEL * sizeof(u16));           // x f16
    u16* pa  = (u16*)alloc(PEL * sizeof(u16));           // agg
    u16* ph0 = (u16*)alloc(PEL * sizeof(u16));
    u16* ph1 = (u16*)alloc(PEL * sizeof(u16));
    u16* pm  = (u16*)alloc((size_t)MROW * 512 * sizeof(u16));   // MLP hidden
    float* pcv = (float*)alloc((size_t)MROW * HH * sizeof(float)); // conv f32 / final h

    // weight converts
    k_cvt<<<(65536 / 8 + 255) / 256, 256, 0, stream>>>(in_w, win, 65536 / 8);
    k_cvt<<<(262144 / 8 + 255) / 256, 256, 0, stream>>>(conv_wl, wl, 262144 / 8);
    k_cvt<<<(262144 / 8 + 255) / 256, 256, 0, stream>>>(conv_wr, wr, 262144 / 8);
    k_cvt<<<(262144 / 8 + 255) / 256, 256, 0, stream>>>(skip_w, wsk, 262144 / 8);
    k_cvt<<<(131072 / 8 + 255) / 256, 256, 0, stream>>>(mlp_w1, m1, 131072 / 8);
    k_cvt<<<(131072 / 8 + 255) / 256, 256, 0, stream>>>(mlp_w2, m2, 131072 / 8);
    // input convert
    k_cvt<<<(NN * 32 + 255) / 256, 256, 0, stream>>>(x, px, NN * 32);

    // CSR build (parallel scan)
    hipMemsetAsync(deg, 0, (size_t)NN * sizeof(int), stream);
    k_hist<<<(NE + 255) / 256, 256, 0, stream>>>(ei, deg);
    k_scan1<<<NB, 256, 0, stream>>>(deg, tscan, bsum);
    k_scan2<<<1, 256, 0, stream>>>(bsum, boff);
    k_scan3<<<NB, 256, 0, stream>>>(deg, tscan, boff, rs, cur, idg);
    k_fill<<<(NE + 255) / 256, 256, 0, stream>>>(ei, cur, col);

    // input projection + ReLU -> ph0
    launch_gemm<true, false, false, true>(NN, 256, 256, 256, 256,
        px, px, win, win, in_b, nullptr, nullptr, nullptr, ph0, stream);

    u16* hc = ph0;
    u16* hn = ph1;
    for (int l = 0; l < NL; ++l) {
        k_aggregate<<<(NN + 3) / 4, 256, 0, stream>>>(hc, rs, col, idg, pa);
        // conv = [agg | h] @ [wl | wr]^T + bl  (K=512 concat) -> pcv f32
        launch_gemm<false, false, true, false>(NN, 512, 256, 256, 256,
            pa, hc, wl + (size_t)l * 65536, wr + (size_t)l * 65536,
            conv_bl + l * HH, nullptr, nullptr, pcv, nullptr, stream);
        hipMemsetAsync(stats, 0, 2 * HH * sizeof(float), stream);
        k_bn_stats<<<1024, 256, 0, stream>>>(pcv, stats);
        k_bn_finalize<<<1, 256, 0, stream>>>(stats, bn_g + l * HH, bn_b + l * HH, scsh);
        // h_next = relu(BN(conv)) + h @ skip_w^T + skip_b -> hn (f16)
        launch_gemm<false, true, false, true>(NN, 256, 256, 256, 256,
            hc, hc, wsk + (size_t)l * 65536, wsk + (size_t)l * 65536,
            skip_b + l * HH, pcv, scsh, nullptr, hn, stream);
        u16* t = hc; hc = hn; hn = t;
    }
    // MLP hidden = relu(h @ w1^T + b1) -> pm (MROW x 512 f16)
    launch_gemm<true, false, false, true>(NN, 256, 512, 256, 256,
        hc, hc, m1, m1, mlp_b1, nullptr, nullptr, nullptr, pm, stream);
    // h = hidden @ w2^T + b2 -> pcv f32 (K=512: A1 = pm+256, W1 = m2+256)
    launch_gemm<false, false, true, false>(NN, 512, 256, 512, 512,
        pm, pm + 256, m2, m2 + 256, mlp_b2, nullptr, nullptr, pcv, nullptr, stream);

    k_out<<<(NN + 3) / 4, 256, 0, stream>>>(pcv, out_w, out_b, out);
}